// Round 1
// baseline (118.654 us; speedup 1.0000x reference)
//
#include <hip/hip_runtime.h>
#include <math.h>

#define DIM 1184         // 256 + 384 + 320 + 224
#define NV4 296          // DIM / 4
// chunk boundaries in float4 units: [0,64) c0, [64,160) c1, [160,240) c2, [240,296) c3

__global__ __launch_bounds__(256) void normact_kernel(const float* __restrict__ x,
                                                      float* __restrict__ out,
                                                      int rows) {
    const int wave = threadIdx.x >> 6;
    const int lane = threadIdx.x & 63;
    const int row  = blockIdx.x * 4 + wave;
    if (row >= rows) return;   // wave-uniform guard

    const float4* __restrict__ xin = (const float4*)(x  + (size_t)row * DIM);
    float4* __restrict__ xo        = (float4*)(out + (size_t)row * DIM);

    float4 v[5];
    float s[4] = {0.f, 0.f, 0.f, 0.f};

    #pragma unroll
    for (int k = 0; k < 5; ++k) {
        int idx = lane + k * 64;
        if (idx < NV4) {
            float4 t = xin[idx];
            v[k] = t;
            int c = (idx < 64) ? 0 : (idx < 160) ? 1 : (idx < 240) ? 2 : 3;
            s[c] += t.x * t.x + t.y * t.y + t.z * t.z + t.w * t.w;
        }
    }

    // 64-lane butterfly reduction of the 4 per-chunk partial sums
    #pragma unroll
    for (int m = 1; m < 64; m <<= 1) {
        #pragma unroll
        for (int c = 0; c < 4; ++c)
            s[c] += __shfl_xor(s[c], m, 64);
    }

    // per-chunk scalars: n = sqrt(mean(x^2)); scal = act(n)
    const float wrec0 = 1.f / 256.f, wrec1 = 1.f / 384.f,
                wrec2 = 1.f / 320.f, wrec3 = 1.f / 224.f;
    float scal[4];
    {
        float n2, n;
        n2 = s[0] * wrec0; n = (n2 > 0.f) ? sqrtf(n2) : 1.f;
        scal[0] = n / (1.f + __expf(-n));          // silu
        n2 = s[1] * wrec1; n = (n2 > 0.f) ? sqrtf(n2) : 1.f;
        scal[1] = 1.f / (1.f + __expf(-n));        // sigmoid
        n2 = s[2] * wrec2; n = (n2 > 0.f) ? sqrtf(n2) : 1.f;
        scal[2] = tanhf(n);                        // tanh
        n2 = s[3] * wrec3; n = (n2 > 0.f) ? sqrtf(n2) : 1.f;
        scal[3] = n / (1.f + __expf(-n));          // silu
    }

    #pragma unroll
    for (int k = 0; k < 5; ++k) {
        int idx = lane + k * 64;
        if (idx < NV4) {
            int c = (idx < 64) ? 0 : (idx < 160) ? 1 : (idx < 240) ? 2 : 3;
            float f = scal[c];
            float4 t = v[k];
            t.x *= f; t.y *= f; t.z *= f; t.w *= f;
            xo[idx] = t;
        }
    }
}

extern "C" void kernel_launch(void* const* d_in, const int* in_sizes, int n_in,
                              void* d_out, int out_size, void* d_ws, size_t ws_size,
                              hipStream_t stream) {
    const float* x = (const float*)d_in[0];
    float* out = (float*)d_out;
    int rows = in_sizes[0] / DIM;
    int grid = (rows + 3) / 4;
    normact_kernel<<<grid, 256, 0, stream>>>(x, out, rows);
}

// Round 2
// 104.457 us; speedup vs baseline: 1.1359x; 1.1359x over previous
//
#include <hip/hip_runtime.h>
#include <math.h>

#define DIM 1184         // 256 + 384 + 320 + 224
#define NV4 296          // DIM / 4
// chunk boundaries in float4 units: [0,64) c0, [64,160) c1, [160,240) c2, [240,296) c3

typedef __attribute__((ext_vector_type(4))) float f32x4;

__global__ __launch_bounds__(256) void normact_kernel(const float* __restrict__ x,
                                                      float* __restrict__ out,
                                                      int rows) {
    const int wave = threadIdx.x >> 6;
    const int lane = threadIdx.x & 63;
    const int row  = blockIdx.x * 4 + wave;
    if (row >= rows) return;   // wave-uniform guard

    const f32x4* __restrict__ xin = (const f32x4*)(x  + (size_t)row * DIM);
    f32x4* __restrict__ xo        = (f32x4*)(out + (size_t)row * DIM);

    f32x4 v[5];
    float s[4] = {0.f, 0.f, 0.f, 0.f};

    #pragma unroll
    for (int k = 0; k < 5; ++k) {
        int idx = lane + k * 64;
        if (idx < NV4) {
            f32x4 t = __builtin_nontemporal_load(xin + idx);
            v[k] = t;
            int c = (idx < 64) ? 0 : (idx < 160) ? 1 : (idx < 240) ? 2 : 3;
            s[c] += t.x * t.x + t.y * t.y + t.z * t.z + t.w * t.w;
        }
    }

    // 64-lane butterfly reduction of the 4 per-chunk partial sums
    #pragma unroll
    for (int m = 1; m < 64; m <<= 1) {
        #pragma unroll
        for (int c = 0; c < 4; ++c)
            s[c] += __shfl_xor(s[c], m, 64);
    }

    // per-chunk scalars: n = sqrt(mean(x^2)); scal = act(n)
    const float wrec0 = 1.f / 256.f, wrec1 = 1.f / 384.f,
                wrec2 = 1.f / 320.f, wrec3 = 1.f / 224.f;
    float scal[4];
    {
        float n2, n;
        n2 = s[0] * wrec0; n = (n2 > 0.f) ? sqrtf(n2) : 1.f;
        scal[0] = n / (1.f + __expf(-n));          // silu
        n2 = s[1] * wrec1; n = (n2 > 0.f) ? sqrtf(n2) : 1.f;
        scal[1] = 1.f / (1.f + __expf(-n));        // sigmoid
        n2 = s[2] * wrec2; n = (n2 > 0.f) ? sqrtf(n2) : 1.f;
        scal[2] = tanhf(n);                        // tanh
        n2 = s[3] * wrec3; n = (n2 > 0.f) ? sqrtf(n2) : 1.f;
        scal[3] = n / (1.f + __expf(-n));          // silu
    }

    #pragma unroll
    for (int k = 0; k < 5; ++k) {
        int idx = lane + k * 64;
        if (idx < NV4) {
            int c = (idx < 64) ? 0 : (idx < 160) ? 1 : (idx < 240) ? 2 : 3;
            float f = scal[c];
            f32x4 t = v[k];
            t.x *= f; t.y *= f; t.z *= f; t.w *= f;
            __builtin_nontemporal_store(t, xo + idx);
        }
    }
}

extern "C" void kernel_launch(void* const* d_in, const int* in_sizes, int n_in,
                              void* d_out, int out_size, void* d_ws, size_t ws_size,
                              hipStream_t stream) {
    const float* x = (const float*)d_in[0];
    float* out = (float*)d_out;
    int rows = in_sizes[0] / DIM;
    int grid = (rows + 3) / 4;
    normact_kernel<<<grid, 256, 0, stream>>>(x, out, rows);
}